// Round 7
// baseline (1071.378 us; speedup 1.0000x reference)
//
#include <hip/hip_runtime.h>
#include <math.h>

// Problem constants (fixed by the reference)
#define NN 10000
#define EE 160000
#define FF 128
#define RR 20
#define LL 3
#define CUTOFF 3.0f
#define F3 384           // 3*F
#define PI_F 3.14159265358979323846f

// NOTE (round 4 lesson): never pass accumulator arrays to helper functions —
// array params decay to pointers, block SROA, accumulators land in scratch
// (VGPR=52, 22x slowdown). All inner loops fully unrolled, static indices.

// ---------------------------------------------------------------------------
// init: sfeat = emb[z], v = 0, deg = 0
__global__ __launch_bounds__(256) void k_init(const int* __restrict__ z,
                                              const float* __restrict__ emb,
                                              float* __restrict__ sfeat,
                                              float* __restrict__ v,
                                              int* __restrict__ deg) {
    int idx = blockIdx.x * 256 + threadIdx.x;
    if (idx < NN * 3 * FF) v[idx] = 0.f;
    if (idx < NN * FF) {
        int n = idx >> 7, f = idx & 127;
        sfeat[idx] = emb[z[n] * FF + f];
    }
    if (idx < NN) deg[idx] = 0;
}

// ---------------------------------------------------------------------------
// CSR build over LIVE edges (dist^2 < CUT^2): count, scan, fill, permute
__global__ __launch_bounds__(256) void k_count(const int* __restrict__ idx_i,
                                               const int* __restrict__ idx_j,
                                               const float* __restrict__ pos,
                                               int* __restrict__ deg) {
    int e = blockIdx.x * 256 + threadIdx.x;
    if (e >= EE) return;
    int i = idx_i[e], j = idx_j[e];
    float dx = pos[j * 3 + 0] - pos[i * 3 + 0];
    float dy = pos[j * 3 + 1] - pos[i * 3 + 1];
    float dz = pos[j * 3 + 2] - pos[i * 3 + 2];
    float sq = dx * dx + dy * dy + dz * dz;
    if (sq < CUTOFF * CUTOFF) atomicAdd(&deg[i], 1);
}

__global__ __launch_bounds__(1024) void k_scan(const int* __restrict__ deg,
                                               int* __restrict__ rowstart,
                                               int* __restrict__ cursor) {
    __shared__ int sd[1024];
    __shared__ int carry;
    if (threadIdx.x == 0) carry = 0;
    __syncthreads();
    for (int base = 0; base < NN; base += 1024) {
        int i = base + (int)threadIdx.x;
        int val = (i < NN) ? deg[i] : 0;
        sd[threadIdx.x] = val;
        __syncthreads();
        for (int off = 1; off < 1024; off <<= 1) {
            int t = (threadIdx.x >= off) ? sd[threadIdx.x - off] : 0;
            __syncthreads();
            sd[threadIdx.x] += t;
            __syncthreads();
        }
        if (i < NN) {
            int ex = carry + sd[threadIdx.x] - val;   // exclusive prefix
            rowstart[i] = ex;
            cursor[i] = ex;
        }
        __syncthreads();
        if (threadIdx.x == 0) carry += sd[1023];
        __syncthreads();
    }
    if (threadIdx.x == 0) rowstart[NN] = carry;
}

__global__ __launch_bounds__(256) void k_fill(const int* __restrict__ idx_i,
                                              const int* __restrict__ idx_j,
                                              const float* __restrict__ pos,
                                              int* __restrict__ cursor,
                                              int* __restrict__ eids) {
    int e = blockIdx.x * 256 + threadIdx.x;
    if (e >= EE) return;
    int i = idx_i[e], j = idx_j[e];
    float dx = pos[j * 3 + 0] - pos[i * 3 + 0];
    float dy = pos[j * 3 + 1] - pos[i * 3 + 1];
    float dz = pos[j * 3 + 2] - pos[i * 3 + 2];
    float sq = dx * dx + dy * dy + dz * dz;
    if (sq < CUTOFF * CUTOFF) {
        int p = atomicAdd(&cursor[i], 1);
        eids[p] = e;
    }
}

// Materialize CSR payloads: j, (cut,dir), rbf per live slot — turns the edge
// kernel's 3-level pointer chase (eids->idx/rbf->phi) into stream + 1 gather.
__global__ __launch_bounds__(256) void k_permute(const int* __restrict__ idx_i,
                                                 const int* __restrict__ idx_j,
                                                 const float* __restrict__ pos,
                                                 const int* __restrict__ eids,
                                                 const int* __restrict__ rowstart,
                                                 int* __restrict__ j_csr,
                                                 float4* __restrict__ cd_csr,
                                                 float* __restrict__ rbf_csr) {
    int t = blockIdx.x * 256 + threadIdx.x;
    if (t >= rowstart[NN]) return;
    int e = eids[t];
    int i = idx_i[e], j = idx_j[e];
    float dx = pos[j * 3 + 0] - pos[i * 3 + 0];
    float dy = pos[j * 3 + 1] - pos[i * 3 + 1];
    float dz = pos[j * 3 + 2] - pos[i * 3 + 2];
    float sq = dx * dx + dy * dy + dz * dz;
    float dist = sq > 0.f ? sqrtf(sq) : 0.f;
    float inv = dist > 0.f ? 1.f / dist : 0.f;
    float cut = 0.5f * (cosf(PI_F * dist / CUTOFF) + 1.f);
    j_csr[t] = j;
    cd_csr[t] = make_float4(cut, dx * inv, dy * inv, dz * inv);
    float b = PI_F * dist / CUTOFF;
    float* rp = rbf_csr + (size_t)t * RR;
#pragma unroll
    for (int r = 0; r < RR; r++)
        rp[r] = sinf((float)(r + 1) * b) * inv;
}

// ---------------------------------------------------------------------------
// Generic fp32 GEMM, register-tiled. C[:, strip] = act(A_cat @ W + bias)
// A_cat rows = A[row,0:KA] ++ A2[row,0:KTOT-KA]  (A2 null iff KA==KTOT)
// RTILE=32 rows x 128 cols per 256-thr block; thread: 4 rows x 4 cols.
// K-major LDS (stride 36) -> per-k A read is one aligned ds_read_b128.
template <int KTOT, bool SILU>
__global__ __launch_bounds__(256, 4) void k_mlp(const float* __restrict__ A, int KA,
                                                const float* __restrict__ A2,
                                                const float* __restrict__ W,
                                                const float* __restrict__ bias,
                                                float* __restrict__ C, int M, int NOUT) {
    constexpr int STR = 36;
    __shared__ float As[KTOT * STR];
    const int tid = threadIdx.x;
    const int row0 = blockIdx.x * 32;
    const int K2 = KTOT - KA;
    for (int idx = tid; idx < 32 * KTOT; idx += 256) {
        int r = idx / KTOT, k = idx - r * KTOT;    // coalesced global read
        int row = row0 + r;
        float val = 0.f;
        if (row < M) val = (k < KA) ? A[(size_t)row * KA + k] : A2[(size_t)row * K2 + (k - KA)];
        As[k * STR + r] = val;                     // K-major LDS write
    }
    __syncthreads();
    const int cg = tid & 31;             // 32 col groups x 4 cols
    const int rg = tid >> 5;             // 8 row groups x 4 rows
    const int c0 = blockIdx.y * 128 + cg * 4;
    const int r0 = rg * 4;
    float4 acc0, acc1, acc2, acc3;
    {
        float4 b = bias ? *reinterpret_cast<const float4*>(bias + c0)
                        : make_float4(0.f, 0.f, 0.f, 0.f);
        acc0 = b; acc1 = b; acc2 = b; acc3 = b;
    }
    for (int k = 0; k < KTOT; k++) {
        float4 w = *reinterpret_cast<const float4*>(W + (size_t)k * NOUT + c0);
        float4 a = *reinterpret_cast<const float4*>(&As[k * STR + r0]);
        acc0.x += a.x * w.x; acc0.y += a.x * w.y; acc0.z += a.x * w.z; acc0.w += a.x * w.w;
        acc1.x += a.y * w.x; acc1.y += a.y * w.y; acc1.z += a.y * w.z; acc1.w += a.y * w.w;
        acc2.x += a.z * w.x; acc2.y += a.z * w.y; acc2.z += a.z * w.z; acc2.w += a.z * w.w;
        acc3.x += a.w * w.x; acc3.y += a.w * w.y; acc3.z += a.w * w.z; acc3.w += a.w * w.w;
    }
#pragma unroll
    for (int p = 0; p < 4; p++) {
        int row = row0 + r0 + p;
        if (row < M) {
            float4 o = (p == 0) ? acc0 : (p == 1) ? acc1 : (p == 2) ? acc2 : acc3;
            if (SILU) {
                o.x = o.x / (1.f + expf(-o.x)); o.y = o.y / (1.f + expf(-o.y));
                o.z = o.z / (1.f + expf(-o.z)); o.w = o.w / (1.f + expf(-o.w));
            }
            *reinterpret_cast<float4*>(C + (size_t)row * NOUT + c0) = o;
        }
    }
}

// ---------------------------------------------------------------------------
// Dual GEMM sharing one A-tile: CU = A@WU, CV = A@WV  (A [M,128], W [128,128])
// RTILE=32, thread: 4 rows x 4 cols x 2 outputs.
__global__ __launch_bounds__(256, 4) void k_uv(const float* __restrict__ A,
                                               const float* __restrict__ WU,
                                               const float* __restrict__ WV,
                                               float* __restrict__ CU,
                                               float* __restrict__ CV, int M) {
    constexpr int STR = 36;
    __shared__ float As[128 * STR];
    const int tid = threadIdx.x;
    const int row0 = blockIdx.x * 32;
    for (int idx = tid; idx < 32 * 128; idx += 256) {
        int r = idx >> 7, k = idx & 127;
        int row = row0 + r;
        As[k * STR + r] = (row < M) ? A[(size_t)row * 128 + k] : 0.f;
    }
    __syncthreads();
    const int cg = tid & 31, rg = tid >> 5;
    const int c0 = cg * 4;
    const int r0 = rg * 4;
    float4 u0 = make_float4(0.f,0.f,0.f,0.f), u1 = u0, u2 = u0, u3 = u0;
    float4 v0 = u0, v1 = u0, v2 = u0, v3 = u0;
    for (int k = 0; k < 128; k++) {
        float4 wu = *reinterpret_cast<const float4*>(WU + k * 128 + c0);
        float4 wv = *reinterpret_cast<const float4*>(WV + k * 128 + c0);
        float4 a = *reinterpret_cast<const float4*>(&As[k * STR + r0]);
        u0.x += a.x * wu.x; u0.y += a.x * wu.y; u0.z += a.x * wu.z; u0.w += a.x * wu.w;
        u1.x += a.y * wu.x; u1.y += a.y * wu.y; u1.z += a.y * wu.z; u1.w += a.y * wu.w;
        u2.x += a.z * wu.x; u2.y += a.z * wu.y; u2.z += a.z * wu.z; u2.w += a.z * wu.w;
        u3.x += a.w * wu.x; u3.y += a.w * wu.y; u3.z += a.w * wu.z; u3.w += a.w * wu.w;
        v0.x += a.x * wv.x; v0.y += a.x * wv.y; v0.z += a.x * wv.z; v0.w += a.x * wv.w;
        v1.x += a.y * wv.x; v1.y += a.y * wv.y; v1.z += a.y * wv.z; v1.w += a.y * wv.w;
        v2.x += a.z * wv.x; v2.y += a.z * wv.y; v2.z += a.z * wv.z; v2.w += a.z * wv.w;
        v3.x += a.w * wv.x; v3.y += a.w * wv.y; v3.z += a.w * wv.z; v3.w += a.w * wv.w;
    }
#pragma unroll
    for (int p = 0; p < 4; p++) {
        int row = row0 + r0 + p;
        if (row < M) {
            float4 ou = (p == 0) ? u0 : (p == 1) ? u1 : (p == 2) ? u2 : u3;
            float4 ov = (p == 0) ? v0 : (p == 1) ? v1 : (p == 2) ? v2 : v3;
            *reinterpret_cast<float4*>(CU + (size_t)row * 128 + c0) = ou;
            *reinterpret_cast<float4*>(CV + (size_t)row * 128 + c0) = ov;
        }
    }
}

// ---------------------------------------------------------------------------
// Node-centric edge accumulation (no atomics). blockIdx.y = feature half.
// 256-thr block = 4 waves = 4 nodes; wave handles 64 features (fb) of all
// three splits. CSR payload streams (j, cut+dir, rbf) are sequential; the
// only gathers are phi[j]/vold[j] (1-level chain). rr-outer contraction keeps
// VGPR low; sW holds only this half's 192 weight columns (15.75 KB).
__global__ __launch_bounds__(256) void k_edge_node(const int* __restrict__ rowstart,
                                                   const int* __restrict__ j_csr,
                                                   const float4* __restrict__ cd_csr,
                                                   const float* __restrict__ rbf_csr,
                                                   const float* __restrict__ phi,
                                                   const float* __restrict__ vold,
                                                   const float* __restrict__ rbf_w,
                                                   const float* __restrict__ rbf_b,
                                                   float* __restrict__ sfeat,
                                                   float* __restrict__ vnew) {
    const int hf = blockIdx.y;
    __shared__ float sW[(RR + 1) * 192];   // rows 0..RR-1 weights, row RR bias
    for (int idx = threadIdx.x; idx < (RR + 1) * 192; idx += 256) {
        int rr = idx / 192, lc = idx - rr * 192;
        int gc = (lc >> 6) * 128 + hf * 64 + (lc & 63);
        sW[idx] = (rr < RR) ? rbf_w[rr * F3 + gc] : rbf_b[gc];
    }
    __syncthreads();
    const int wave = threadIdx.x >> 6, lane = threadIdx.x & 63;
    const int n = blockIdx.x * 4 + wave;       // grid.x*4 == NN exactly
    const int fb = hf * 64 + lane;             // owned feature in [0,128)
    const float bvv = sW[RR * 192 + lane];
    const float bss = sW[RR * 192 + 64 + lane];
    const float bvs = sW[RR * 192 + 128 + lane];
    float as = 0.f, ad0 = 0.f, ad1 = 0.f, ad2 = 0.f;
    int t = rowstart[n];
    const int t1 = rowstart[n + 1];
    for (; t + 1 < t1; t += 2) {
        const int j0 = j_csr[t], j1 = j_csr[t + 1];
        const float4 cA = cd_csr[t], cB = cd_csr[t + 1];
        const float* rp0 = rbf_csr + (size_t)t * RR;       // rows 16B-aligned
        float avv0 = bvv, ass0 = bss, avs0 = bvs;
        float avv1 = bvv, ass1 = bss, avs1 = bvs;
#pragma unroll
        for (int q = 0; q < 5; q++) {
            const float4 r0 = *reinterpret_cast<const float4*>(rp0 + q * 4);
            const float4 r1 = *reinterpret_cast<const float4*>(rp0 + RR + q * 4);
            {
                const float wvv = sW[(4*q+0)*192 + lane], wss = sW[(4*q+0)*192 + 64 + lane], wvs = sW[(4*q+0)*192 + 128 + lane];
                avv0 += r0.x * wvv; ass0 += r0.x * wss; avs0 += r0.x * wvs;
                avv1 += r1.x * wvv; ass1 += r1.x * wss; avs1 += r1.x * wvs;
            }
            {
                const float wvv = sW[(4*q+1)*192 + lane], wss = sW[(4*q+1)*192 + 64 + lane], wvs = sW[(4*q+1)*192 + 128 + lane];
                avv0 += r0.y * wvv; ass0 += r0.y * wss; avs0 += r0.y * wvs;
                avv1 += r1.y * wvv; ass1 += r1.y * wss; avs1 += r1.y * wvs;
            }
            {
                const float wvv = sW[(4*q+2)*192 + lane], wss = sW[(4*q+2)*192 + 64 + lane], wvs = sW[(4*q+2)*192 + 128 + lane];
                avv0 += r0.z * wvv; ass0 += r0.z * wss; avs0 += r0.z * wvs;
                avv1 += r1.z * wvv; ass1 += r1.z * wss; avs1 += r1.z * wvs;
            }
            {
                const float wvv = sW[(4*q+3)*192 + lane], wss = sW[(4*q+3)*192 + 64 + lane], wvs = sW[(4*q+3)*192 + 128 + lane];
                avv0 += r0.w * wvv; ass0 += r0.w * wss; avs0 += r0.w * wvs;
                avv1 += r1.w * wvv; ass1 += r1.w * wss; avs1 += r1.w * wvs;
            }
        }
        const size_t p0 = (size_t)j0 * F3 + fb;
        const size_t p1 = (size_t)j1 * F3 + fb;
        const float pvv0 = phi[p0]       * (avv0 * cA.x);
        const float pss0 = phi[p0 + 128] * (ass0 * cA.x);
        const float pvs0 = phi[p0 + 256] * (avs0 * cA.x);
        const float pvv1 = phi[p1]       * (avv1 * cB.x);
        const float pss1 = phi[p1 + 128] * (ass1 * cB.x);
        const float pvs1 = phi[p1 + 256] * (avs1 * cB.x);
        as  += pss0 + pss1;
        ad0 += vold[p0]       * pvv0 + pvs0 * cA.y + vold[p1]       * pvv1 + pvs1 * cB.y;
        ad1 += vold[p0 + 128] * pvv0 + pvs0 * cA.z + vold[p1 + 128] * pvv1 + pvs1 * cB.z;
        ad2 += vold[p0 + 256] * pvv0 + pvs0 * cA.w + vold[p1 + 256] * pvv1 + pvs1 * cB.w;
    }
    if (t < t1) {                              // odd remainder edge
        const int j0 = j_csr[t];
        const float4 cA = cd_csr[t];
        const float* rp0 = rbf_csr + (size_t)t * RR;
        float avv0 = bvv, ass0 = bss, avs0 = bvs;
#pragma unroll
        for (int q = 0; q < 5; q++) {
            const float4 r0 = *reinterpret_cast<const float4*>(rp0 + q * 4);
            avv0 += r0.x * sW[(4*q+0)*192 + lane] + r0.y * sW[(4*q+1)*192 + lane]
                  + r0.z * sW[(4*q+2)*192 + lane] + r0.w * sW[(4*q+3)*192 + lane];
            ass0 += r0.x * sW[(4*q+0)*192 + 64 + lane] + r0.y * sW[(4*q+1)*192 + 64 + lane]
                  + r0.z * sW[(4*q+2)*192 + 64 + lane] + r0.w * sW[(4*q+3)*192 + 64 + lane];
            avs0 += r0.x * sW[(4*q+0)*192 + 128 + lane] + r0.y * sW[(4*q+1)*192 + 128 + lane]
                  + r0.z * sW[(4*q+2)*192 + 128 + lane] + r0.w * sW[(4*q+3)*192 + 128 + lane];
        }
        const size_t p0 = (size_t)j0 * F3 + fb;
        const float pvv0 = phi[p0]       * (avv0 * cA.x);
        const float pss0 = phi[p0 + 128] * (ass0 * cA.x);
        const float pvs0 = phi[p0 + 256] * (avs0 * cA.x);
        as  += pss0;
        ad0 += vold[p0]       * pvv0 + pvs0 * cA.y;
        ad1 += vold[p0 + 128] * pvv0 + pvs0 * cA.z;
        ad2 += vold[p0 + 256] * pvv0 + pvs0 * cA.w;
    }
    sfeat[n * FF + fb] += as;                  // node+half owned: no atomics
    const size_t vb0 = (size_t)n * F3 + fb;
    vnew[vb0]       = vold[vb0]       + ad0;
    vnew[vb0 + 128] = vold[vb0 + 128] + ad1;
    vnew[vb0 + 256] = vold[vb0 + 256] + ad2;
}

// ---------------------------------------------------------------------------
// per (n,g): vnorm = safe_norm(Vv[n,:,g]), dot = <Uv,Vv>
__global__ __launch_bounds__(256) void k_normdot(const float* __restrict__ Uv,
                                                 const float* __restrict__ Vv,
                                                 float* __restrict__ vnorm,
                                                 float* __restrict__ dotb) {
    int idx = blockIdx.x * 256 + threadIdx.x;
    if (idx >= NN * FF) return;
    int n = idx >> 7, g = idx & 127;
    const float* uv = Uv + (size_t)n * F3 + g;
    const float* vv = Vv + (size_t)n * F3 + g;
    float u0 = uv[0], u1 = uv[FF], u2 = uv[2 * FF];
    float w0 = vv[0], w1 = vv[FF], w2 = vv[2 * FF];
    float sq = w0 * w0 + w1 * w1 + w2 * w2;
    vnorm[idx] = sq > 0.f ? sqrtf(sq) : 0.f;
    dotb[idx] = u0 * w0 + u1 * w1 + u2 * w2;
}

// ---------------------------------------------------------------------------
// gated update: v[n,:,g] += Uv[n,:,g]*a_vv;  s[n,g] += a_ss + a_sv*dot
__global__ __launch_bounds__(256) void k_update(const float* __restrict__ a,
                                                const float* __restrict__ Uv,
                                                const float* __restrict__ dotb,
                                                float* __restrict__ v,
                                                float* __restrict__ sfeat) {
    int idx = blockIdx.x * 256 + threadIdx.x;
    if (idx >= NN * FF) return;
    int n = idx >> 7, g = idx & 127;
    float avv = a[(size_t)n * F3 + g];
    float asv = a[(size_t)n * F3 + 128 + g];
    float ass = a[(size_t)n * F3 + 256 + g];
#pragma unroll
    for (int d = 0; d < 3; d++)
        v[(size_t)n * F3 + d * FF + g] += Uv[(size_t)n * F3 + d * FF + g] * avv;
    sfeat[idx] += ass + asv * dotb[idx];
}

// ---------------------------------------------------------------------------
// transpose internal v[N,3,F] -> output vfeat[N,F,3]
__global__ __launch_bounds__(256) void k_outv(const float* __restrict__ v,
                                              float* __restrict__ outv) {
    int idx = blockIdx.x * 256 + threadIdx.x;
    if (idx >= NN * FF * 3) return;
    int n = idx / F3;
    int rem = idx - n * F3;
    int f = rem / 3;
    int d = rem - f * 3;
    outv[idx] = v[n * F3 + d * FF + f];
}

// ---------------------------------------------------------------------------
extern "C" void kernel_launch(void* const* d_in, const int* in_sizes, int n_in,
                              void* d_out, int out_size, void* d_ws, size_t ws_size,
                              hipStream_t stream) {
    const int*   z      = (const int*)d_in[0];
    const float* pos    = (const float*)d_in[1];
    const int*   idx_i  = (const int*)d_in[2];
    const int*   idx_j  = (const int*)d_in[3];
    const float* emb    = (const float*)d_in[4];
    const float* msg_w1 = (const float*)d_in[5];
    const float* msg_b1 = (const float*)d_in[6];
    const float* msg_w2 = (const float*)d_in[7];
    const float* msg_b2 = (const float*)d_in[8];
    const float* rbf_w  = (const float*)d_in[9];
    const float* rbf_b  = (const float*)d_in[10];
    const float* upd_U  = (const float*)d_in[11];
    const float* upd_V  = (const float*)d_in[12];
    const float* upd_w1 = (const float*)d_in[13];
    const float* upd_b1 = (const float*)d_in[14];
    const float* upd_w2 = (const float*)d_in[15];
    const float* upd_b2 = (const float*)d_in[16];

    float* sfeat = (float*)d_out;            // [N,F]
    float* outv  = sfeat + NN * FF;          // [N,F,3]

    float* ws    = (float*)d_ws;
    float* va    = ws;                       // [N,3,F] ping
    float* vb    = va + NN * F3;             // [N,3,F] pong
    float* phi   = vb + NN * F3;             // [N,3F] (also reused as 'a')
    float* h     = phi + NN * F3;            // [N,F]
    float* Uvb   = h + NN * FF;              // [N,3,F]
    float* Vvb   = Uvb + NN * F3;            // [N,3,F]
    float* vnorm = Vvb + NN * F3;            // [N,F]
    float* dotb  = vnorm + NN * FF;          // [N,F]
    float4* cd_csr = (float4*)(dotb + NN * FF);   // [E] (16B-aligned: offset %4==0)
    float* rbf_csr = (float*)(cd_csr + EE);       // [E,R]
    int*   j_csr     = (int*)(rbf_csr + (size_t)EE * RR);  // [E]
    int*   deg       = j_csr + EE;           // [N]
    int*   rowstart  = deg + NN;             // [N+1]
    int*   cursor    = rowstart + NN + 1;    // [N]
    int*   eids      = cursor + NN;          // [E]

    const dim3 blk(256);
    const dim3 gE((EE + 255) / 256);
    k_init<<<dim3((NN * 3 * FF) / 256), blk, 0, stream>>>(z, emb, sfeat, va, deg);
    k_count<<<gE, blk, 0, stream>>>(idx_i, idx_j, pos, deg);
    k_scan<<<dim3(1), dim3(1024), 0, stream>>>(deg, rowstart, cursor);
    k_fill<<<gE, blk, 0, stream>>>(idx_i, idx_j, pos, cursor, eids);
    k_permute<<<gE, blk, 0, stream>>>(idx_i, idx_j, pos, eids, rowstart,
                                      j_csr, cd_csr, rbf_csr);

    float* vcur = va;
    float* vnxt = vb;
    const int gN32  = (NN + 31) / 32;        // 313
    const int g3N32 = (3 * NN + 31) / 32;    // 938

    for (int l = 0; l < LL; l++) {
        const float* mw1 = msg_w1 + l * FF * FF;
        const float* mb1 = msg_b1 + l * FF;
        const float* mw2 = msg_w2 + l * FF * F3;
        const float* mb2 = msg_b2 + l * F3;
        const float* rw  = rbf_w + l * RR * F3;
        const float* rb  = rbf_b + l * F3;
        const float* uU  = upd_U + l * FF * FF;
        const float* uV  = upd_V + l * FF * FF;
        const float* uw1 = upd_w1 + l * 2 * FF * FF;
        const float* ub1 = upd_b1 + l * FF;
        const float* uw2 = upd_w2 + l * FF * F3;
        const float* ub2 = upd_b2 + l * F3;

        // h = silu(s@w1+b1); phi = h@w2+b2
        k_mlp<128, true><<<dim3(gN32, 1), blk, 0, stream>>>(sfeat, 128, nullptr, mw1, mb1, h, NN, 128);
        k_mlp<128, false><<<dim3(gN32, 3), blk, 0, stream>>>(h, 128, nullptr, mw2, mb2, phi, NN, F3);

        // node-centric message aggregation: sfeat += ..., vnxt = vcur + dv
        k_edge_node<<<dim3(NN / 4, 2), blk, 0, stream>>>(rowstart, j_csr, cd_csr, rbf_csr,
                                                         phi, vcur, rw, rb, sfeat, vnxt);

        // Uv/Vv dual GEMM on vnxt
        k_uv<<<dim3(g3N32), blk, 0, stream>>>(vnxt, uU, uV, Uvb, Vvb, 3 * NN);
        k_normdot<<<dim3((NN * FF) / 256), blk, 0, stream>>>(Uvb, Vvb, vnorm, dotb);

        // h = silu([vnorm|sfeat]@w1+b1); a = h@w2+b2 (into phi buffer)
        k_mlp<256, true><<<dim3(gN32, 1), blk, 0, stream>>>(vnorm, 128, sfeat, uw1, ub1, h, NN, 128);
        k_mlp<128, false><<<dim3(gN32, 3), blk, 0, stream>>>(h, 128, nullptr, uw2, ub2, phi, NN, F3);

        // gating epilogue (updates vnxt, sfeat)
        k_update<<<dim3((NN * FF) / 256), blk, 0, stream>>>(phi, Uvb, dotb, vnxt, sfeat);

        // ping-pong
        float* tmp = vcur; vcur = vnxt; vnxt = tmp;
    }

    k_outv<<<dim3((NN * FF * 3 + 255) / 256), blk, 0, stream>>>(vcur, outv);
}